// Round 9
// baseline (473.338 us; speedup 1.0000x reference)
//
#include <hip/hip_runtime.h>
#include <math.h>

#define SEQ 512
#define NORD 256
#define MODES 32
#define KBIG (NORD*MODES*2)   // 16384
#define PI_F 3.14159265358979323846f

typedef _Float16 half8 __attribute__((ext_vector_type(8)));
typedef float floatx4 __attribute__((ext_vector_type(4)));

// ---------------- latency-tolerant f32 GEMM: 32x32 tile, BK=64, reg prefetch ----

struct GJob {
  const float* A; const float* B; float* C; const float* scale_ptr;
  int M, N, lda, k0, k1, atomic;
};
struct GJobs { GJob j[6]; };

__global__ __launch_bounds__(256) void gemm32_k(GJobs P) {
  GJob jb = P.j[blockIdx.z];
  int col0 = blockIdx.x * 32;
  int row0 = blockIdx.y * 32;
  if (row0 >= jb.M || col0 >= jb.N) return;
  __shared__ float As[64][34];   // [k][m]; pad 34 keeps b64 reads aligned, 4-way store conflicts only
  __shared__ float Bs[64][36];   // [k][n]; pad 36 keeps float4 stores 16B-aligned
  int tid = threadIdx.x;
  int tx = tid & 15, ty = tid >> 4;
  const float* A = jb.A; const float* B = jb.B;
  int M = jb.M, N = jb.N, lda = jb.lda;
  int kcA = (tid & 15) * 4, rA = tid >> 4;
  int ccB = (tid & 7) * 4, kkB = tid >> 3;
  int gr0 = row0 + rA, gr1 = row0 + rA + 16;
  const float4 z4 = make_float4(0.f, 0.f, 0.f, 0.f);
  float4 a0, a1, b0, b1;
  {
    int kb = jb.k0;
    a0 = (gr0 < M) ? *(const float4*)&A[(size_t)gr0 * lda + kb + kcA] : z4;
    a1 = (gr1 < M) ? *(const float4*)&A[(size_t)gr1 * lda + kb + kcA] : z4;
    b0 = *(const float4*)&B[(size_t)(kb + kkB) * N + col0 + ccB];
    b1 = *(const float4*)&B[(size_t)(kb + kkB + 32) * N + col0 + ccB];
  }
  float acc00 = 0.f, acc01 = 0.f, acc10 = 0.f, acc11 = 0.f;
  for (int kb = jb.k0; kb < jb.k1; kb += 64) {
    As[kcA+0][rA] = a0.x; As[kcA+1][rA] = a0.y; As[kcA+2][rA] = a0.z; As[kcA+3][rA] = a0.w;
    As[kcA+0][rA+16] = a1.x; As[kcA+1][rA+16] = a1.y; As[kcA+2][rA+16] = a1.z; As[kcA+3][rA+16] = a1.w;
    *(float4*)&Bs[kkB][ccB] = b0;
    *(float4*)&Bs[kkB+32][ccB] = b1;
    __syncthreads();
    if (kb + 64 < jb.k1) {
      int kn = kb + 64;
      a0 = (gr0 < M) ? *(const float4*)&A[(size_t)gr0 * lda + kn + kcA] : z4;
      a1 = (gr1 < M) ? *(const float4*)&A[(size_t)gr1 * lda + kn + kcA] : z4;
      b0 = *(const float4*)&B[(size_t)(kn + kkB) * N + col0 + ccB];
      b1 = *(const float4*)&B[(size_t)(kn + kkB + 32) * N + col0 + ccB];
    }
    #pragma unroll
    for (int k = 0; k < 64; k++) {
      float2 av = *(float2*)&As[k][ty * 2];
      float2 bv = *(float2*)&Bs[k][tx * 2];
      acc00 += av.x * bv.x; acc01 += av.x * bv.y;
      acc10 += av.y * bv.x; acc11 += av.y * bv.y;
    }
    __syncthreads();
  }
  float sc = jb.scale_ptr ? *jb.scale_ptr : 1.f;
  int gr = row0 + ty * 2, gc = col0 + tx * 2;
  float v00 = acc00 * sc, v01 = acc01 * sc, v10 = acc10 * sc, v11 = acc11 * sc;
  if (jb.atomic) {
    if (gr < M)     { atomicAdd(&jb.C[(size_t)gr * N + gc], v00);     atomicAdd(&jb.C[(size_t)gr * N + gc + 1], v01); }
    if (gr + 1 < M) { atomicAdd(&jb.C[(size_t)(gr+1) * N + gc], v10); atomicAdd(&jb.C[(size_t)(gr+1) * N + gc + 1], v11); }
  } else {
    if (gr < M)     { jb.C[(size_t)gr * N + gc] = v00;     jb.C[(size_t)gr * N + gc + 1] = v01; }
    if (gr + 1 < M) { jb.C[(size_t)(gr+1) * N + gc] = v10; jb.C[(size_t)(gr+1) * N + gc + 1] = v11; }
  }
}

// ---------------- merged prep: RevIN + LDS-tiled transposes + kry init + zeroing
// + (optionally) wbigT weight build in blocks [1731, 1731+nW) ------------------

__global__ __launch_bounds__(256) void prep2_k(const float* __restrict__ x_enc,
                                               const float* __restrict__ aw,
                                               const float* __restrict__ ab,
                                               float* __restrict__ F,
                                               float* __restrict__ stats,
                                               const float* A0, const float* A1, const float* A2,
                                               const float* B0, const float* B1, const float* B2,
                                               const float* E0, const float* E1, const float* E2,
                                               float* R, float* Kry, float* Et, float* Z,
                                               unsigned* __restrict__ tick,
                                               const float* wr0, const float* wi0,
                                               const float* wr1, const float* wi1,
                                               const float* wr2, const float* wi2,
                                               _Float16* __restrict__ Wt) {
  __shared__ float tile[32][33];
  __shared__ float ws1[4], ws2[4];
  __shared__ float mean_s, istd_s;
  int bid = blockIdx.x;
  int tid = threadIdx.x;
  if (bid < 512) {
    // ---- RevIN ----
    int row = bid;
    int b = row >> 5, c = row & 31;
    const float* xp = x_enc + (size_t)b * SEQ * 32 + c;
    float v0 = xp[(size_t)tid * 32];
    float v1 = xp[(size_t)(tid + 256) * 32];
    float s = v0 + v1, s2 = v0 * v0 + v1 * v1;
    for (int off = 32; off; off >>= 1) {
      s  += __shfl_down(s,  off, 64);
      s2 += __shfl_down(s2, off, 64);
    }
    int wid = tid >> 6, lane = tid & 63;
    if (lane == 0) { ws1[wid] = s; ws2[wid] = s2; }
    __syncthreads();
    if (tid == 0) {
      float t1 = ws1[0] + ws1[1] + ws1[2] + ws1[3];
      float t2 = ws2[0] + ws2[1] + ws2[2] + ws2[3];
      float mean = t1 / 512.f;
      float var = t2 / 512.f - mean * mean;
      float sd = sqrtf(var + 1e-5f);
      mean_s = mean; istd_s = 1.f / sd;
      stats[row] = mean; stats[512 + row] = sd;
    }
    __syncthreads();
    float w = aw[c], bb = ab[c];
    float m = mean_s, is = istd_s;
    F[(size_t)row * SEQ + tid]       = (v0 - m) * is * w + bb;
    F[(size_t)row * SEQ + tid + 256] = (v1 - m) * is * w + bb;
  } else if (bid < 704) {
    // ---- R[m][i2] = A[i2][m], 32x32 LDS tiles, both sides coalesced ----
    int b2 = bid - 512;
    int scl = b2 >> 6, t = b2 & 63;
    int ti = t >> 3, tm = t & 7;
    const float* A = scl == 0 ? A0 : (scl == 1 ? A1 : A2);
    float* Rd = R + (size_t)scl * 2 * 65536;
    int tx = tid & 31, ty0 = tid >> 5;
    int i0 = ti * 32, m0 = tm * 32;
    #pragma unroll
    for (int r = 0; r < 4; r++) {
      int ty = ty0 + r * 8;
      tile[ty][tx] = A[(size_t)(i0 + ty) * 256 + m0 + tx];
    }
    __syncthreads();
    #pragma unroll
    for (int r = 0; r < 4; r++) {
      int ty = ty0 + r * 8;
      Rd[(size_t)(m0 + ty) * 256 + i0 + tx] = tile[tx][ty];
    }
  } else if (bid < 1088) {
    // ---- Et[o][p] = E[base+p][o], 32x32 LDS tiles ----
    int b2 = bid - 704;
    int scl = b2 >> 7, t = b2 & 127;
    int tp = t >> 3, to = t & 7;
    const float* E; int rows;
    if (scl == 0) { E = E0; rows = 512; }
    else if (scl == 1) { E = E1; rows = 1024; }
    else { E = E2; rows = 2048; }
    int base = rows - 512;
    int p0 = tp * 32, o0 = to * 32;
    int tx = tid & 31, ty0 = tid >> 5;
    #pragma unroll
    for (int r = 0; r < 4; r++) {
      int ty = ty0 + r * 8;
      tile[ty][tx] = E[(size_t)(base + p0 + ty) * 256 + o0 + tx];
    }
    __syncthreads();
    #pragma unroll
    for (int r = 0; r < 4; r++) {
      int ty = ty0 + r * 8;
      Et[(size_t)scl * 131072 + (size_t)(o0 + ty) * 512 + p0 + tx] = tile[tx][ty];
    }
  } else if (bid < 1091) {
    int scl = bid - 1088;
    const float* B = scl == 0 ? B0 : (scl == 1 ? B1 : B2);
    Kry[(size_t)scl * 512 * 256 + tid] = B[tid];
    if (bid == 1088 && tid < 64) tick[tid] = 0u;   // split-K ticket counters
  } else if (bid < 1731) {
    int idx = (bid - 1091) * 256 + tid;   // 640 blocks * 256 = 163840 float4 = 655360 floats
    ((float4*)Z)[idx] = make_float4(0.f, 0.f, 0.f, 0.f);
  } else {
    // ---- wbigT: f16 weights in fragment order, x4096 scale (nS==3 path) ----
    int bg = bid - 1731;
    int slab = bg >> 8;
    int s = slab;
    int r = bg & 255;
    int og = r >> 3, iq = r & 7;
    const float* wr = s == 0 ? wr0 : (s == 1 ? wr1 : wr2);
    const float* wi = s == 0 ? wi0 : (s == 1 ? wi1 : wi2);
    unsigned int* Wd = (unsigned int*)(Wt + (size_t)slab * 4194304);
    int ol = tid >> 5, k = tid & 31;
    int o = og * 8 + ol;
    float sn, cn; __sincosf((2.f * PI_F / 512.f) * (float)k, &sn, &cn);
    float g = ((k == 0) ? (1.f / 512.f) : (2.f / 512.f)) * 4096.f;
    float gc = g * cn, gs = g * sn;
    size_t obase = (size_t)(o >> 4) * 512;
    int osub = (((k >> 2) & 3) * 16 + (o & 15)) * 4 + (k & 3);
    for (int ii = 0; ii < 32; ii++) {
      int i = iq * 32 + ii;
      float a = wr[(size_t)i * 8192 + o * 32 + k];
      float b = wi[(size_t)i * 8192 + o * 32 + k];
      float v0 = gc * a + gs * b;
      float v1 = gs * a - gc * b;
      _Float16 h0 = (_Float16)v0, h1 = (_Float16)v1;
      unsigned short u0, u1;
      __builtin_memcpy(&u0, &h0, 2); __builtin_memcpy(&u1, &h1, 2);
      Wd[(obase + (size_t)(i * 2 + (k >> 4))) * 256 + osub] = (unsigned int)u0 | ((unsigned int)u1 << 16);
    }
  }
}

// ---------------- qbuild: 2-phase chunked prefix over m (batched over scales) ----
//
// Q is written in MFMA-FRAGMENT ORDER so the GEMM streams it with zero LDS
// address math. All trig args are (2pi/512)*t, t in [0,512): per-block LDS
// table of (cos, -sin) built with the same __sincosf -> bit-identical values.

__global__ __launch_bounds__(256) void qbuildB_k(const float* __restrict__ Kry,
                                                 const float2* __restrict__ Pp,
                                                 _Float16* __restrict__ Qf, int s0) {
  int bg = blockIdx.x;
  int slab = bg >> 8;
  int s = s0 + slab;
  int r = bg & 255;
  int ig = r & 31, c = r >> 5;
  const float* Kry_s = Kry + (size_t)s * 131072;
  const float2* P = Pp + (size_t)s * 65536;
  uint4* Qd4 = (uint4*)(Qf + (size_t)slab * 8388608);
  int tid = threadIdx.x;
  int k = tid & 31, il = tid >> 5;
  int i = ig * 8 + il;
  __shared__ __align__(16) unsigned int buf[16 * 260];  // stride 260: bank step 4, 2-way only
  __shared__ float2 tbl[512];                           // (cos, -sin) per 512th turn
  {
    const float step = 2.f * PI_F / 512.f;
    for (int t = tid; t < 512; t += 256) {
      float sn, cn; __sincosf(step * (float)t, &sn, &cn);
      tbl[t] = make_float2(cn, -sn);
    }
  }
  __syncthreads();
  float ar = 0.f, ai = 0.f;
  for (int cp = 0; cp < c; cp++) {
    float2 p = P[(size_t)(cp * 32 + k) * 256 + i];
    ar += p.x; ai += p.y;
  }
  int m0 = c * 64;
  int st_low = tid & 15;
  int part_base = tid >> 4;      // 0..15
  for (int mb = 0; mb < 64; mb += 16) {
    #pragma unroll
    for (int mm = 0; mm < 16; mm++) {
      int m = m0 + mb + mm;
      float kap = Kry_s[(size_t)m * 256 + i];
      float2 cs = tbl[(k * m) & 511];
      ar += kap * cs.x; ai += kap * cs.y;
      int st = 511 - m;
      float2 cs2 = tbl[(k * st) & 511];
      float cn2 = cs2.x, sn2 = -cs2.y;
      float qr = ar * cn2 + ai * sn2;
      float qi = ai * cn2 - ar * sn2;
      qr = fminf(fmaxf(qr, -60000.f), 60000.f);
      qi = fminf(fmaxf(qi, -60000.f), 60000.f);
      _Float16 h0 = (_Float16)qr, h1 = (_Float16)qi;
      unsigned short u0, u1;
      __builtin_memcpy(&u0, &h0, 2); __builtin_memcpy(&u1, &h1, 2);
      buf[(st & 15) * 260 + il * 32 + k] = (unsigned int)u0 | ((unsigned int)u1 << 16);
    }
    __syncthreads();
    int st_base = 496 - m0 - mb;          // multiple of 16
    int st = st_base + st_low;
    size_t rowbase = (size_t)(st >> 4) * 512;
    #pragma unroll
    for (int p = 0; p < 4; p++) {
      int part = part_base + p * 16;      // 0..63 = (il<<3)|k4
      int ilw = part >> 3, k4 = part & 7;
      int iw = ig * 8 + ilw;
      size_t g = (rowbase + (size_t)(iw * 2 + (k4 >> 2))) * 64
               + (size_t)((k4 & 3) * 16 + st_low);
      Qd4[g] = *(const uint4*)&buf[st_low * 260 + ilw * 32 + k4 * 4];
    }
    __syncthreads();
  }
}

// ---------------- merged: qbuildA (bid<nA) + Wbig^T build (bid>=nA) -------------
// (wbigT branch only used on the nS==1 fallback path; nS==3 does wbigT in prep2)

__global__ __launch_bounds__(256) void qw_k(const float* __restrict__ Kry,
                                            float2* __restrict__ Pp,
                                            const float* wr0, const float* wi0,
                                            const float* wr1, const float* wi1,
                                            const float* wr2, const float* wi2,
                                            _Float16* __restrict__ Wt, int s0, int nA) {
  __shared__ float2 tbl[512];
  int bid = blockIdx.x;
  int tid = threadIdx.x;
  if (bid < nA) {
    // ---- qbuildA: chunk partial DFT sums (table-driven; k is block-uniform
    // so the tbl read is an LDS broadcast) ----
    {
      const float step = 2.f * PI_F / 512.f;
      for (int t = tid; t < 512; t += 256) {
        float sn, cn; __sincosf(step * (float)t, &sn, &cn);
        tbl[t] = make_float2(cn, -sn);
      }
    }
    __syncthreads();
    int bg = bid;
    int s = s0 + (bg >> 8);
    int r = bg & 255;
    int k = r & 31, c = r >> 5;
    const float* Kry_s = Kry + (size_t)s * 131072;
    float2* P = Pp + (size_t)s * 65536;
    int i = tid;
    float ar = 0.f, ai = 0.f;
    int m0 = c * 64;
    for (int mm = 0; mm < 64; mm++) {
      int m = m0 + mm;
      float kap = Kry_s[(size_t)m * 256 + i];
      float2 cs = tbl[(k * m) & 511];
      ar += kap * cs.x; ai += kap * cs.y;
    }
    P[(size_t)(c * 32 + k) * 256 + i] = make_float2(ar, ai);
  } else {
    // ---- wbigT: f16 weights in fragment order, x4096 scale ----
    int bg = bid - nA;
    int slab = bg >> 8;
    int s = s0 + slab;
    int r = bg & 255;
    int og = r >> 3, iq = r & 7;
    const float* wr = s == 0 ? wr0 : (s == 1 ? wr1 : wr2);
    const float* wi = s == 0 ? wi0 : (s == 1 ? wi1 : wi2);
    unsigned int* Wd = (unsigned int*)(Wt + (size_t)slab * 4194304);
    int ol = tid >> 5, k = tid & 31;
    int o = og * 8 + ol;
    float sn, cn; __sincosf((2.f * PI_F / 512.f) * (float)k, &sn, &cn);
    float g = ((k == 0) ? (1.f / 512.f) : (2.f / 512.f)) * 4096.f;
    float gc = g * cn, gs = g * sn;
    size_t obase = (size_t)(o >> 4) * 512;
    int osub = (((k >> 2) & 3) * 16 + (o & 15)) * 4 + (k & 3);
    for (int ii = 0; ii < 32; ii++) {
      int i = iq * 32 + ii;
      float a = wr[(size_t)i * 8192 + o * 32 + k];
      float b = wi[(size_t)i * 8192 + o * 32 + k];
      float v0 = gc * a + gs * b;
      float v1 = gs * a - gc * b;
      _Float16 h0 = (_Float16)v0, h1 = (_Float16)v1;
      unsigned short u0, u1;
      __builtin_memcpy(&u0, &h0, 2); __builtin_memcpy(&u1, &h1, 2);
      Wd[(obase + (size_t)(i * 2 + (k >> 4))) * 256 + osub] = (unsigned int)u0 | ((unsigned int)u1 << 16);
    }
  }
}

// ---------------- U = Q @ Wb, LDS-staged dbuf MFMA, split-K via partials --------
// Epilogue: plain stores to per-block partial tile, device fence + ticket;
// 16th block for a tile sums the 16 partials (fixed order, deterministic) and
// writes U. Replaces 6.3M cross-XCD atomicAdds (r7 diagnosis: atomic drain
// dominated the dispatch).

__global__ __launch_bounds__(256) void umfma_k(const _Float16* __restrict__ Qf,
                                               const _Float16* __restrict__ Wt,
                                               float* __restrict__ U,
                                               float* __restrict__ Upart,
                                               unsigned* __restrict__ tick, int s0) {
  __shared__ __align__(16) _Float16 lds[2][12288];   // 24 frags x 512 halfs x dbuf = 48KB
  __shared__ int ticket_s;
  int kslab = blockIdx.x;          // 0..15
  int y = blockIdx.y;              // 0..15
  int slab = blockIdx.z;
  int s = s0 + slab;
  int mtb = y >> 1, ntb = y & 1;   // 8 x 64-row tiles, 2 x 128-col tiles
  const _Float16* Q = Qf + (size_t)slab * 8388608;
  const _Float16* W = Wt + (size_t)slab * 4194304;
  float* Us = U + (size_t)s * 131072;
  int tid = threadIdx.x;
  int w = tid >> 6, lane = tid & 63;
  int wm = w >> 1, wn = w & 1;
  int quad = lane >> 4, lm = lane & 15;
  int mt0g = mtb * 4;              // block-local mt 0..3 -> global mt0g..+3
  int nt0g = ntb * 8;              // block-local nt 0..7
  int ktg0 = kslab * 32;
  size_t laneoff = (size_t)lane * 8;

  floatx4 acc[2][4];
  #pragma unroll
  for (int a = 0; a < 2; a++)
    #pragma unroll
    for (int b = 0; b < 4; b++) acc[a][b] = (floatx4)(0.f);

  // stage: 24 fragments (8 A + 16 B), 6 per wave, f*512 halfs into LDS
  auto stage = [&](int ks, int bufi) {
    int ktg = ktg0 + ks * 2;
    #pragma unroll
    for (int q = 0; q < 6; q++) {
      int f = w * 6 + q;
      const _Float16* src;
      if (f < 8) {
        src = Q + (((size_t)(mt0g + (f >> 1)) * 512) + (size_t)(ktg + (f & 1))) * 512;
      } else {
        int g = f - 8;
        src = W + (((size_t)(nt0g + (g >> 1)) * 512) + (size_t)(ktg + (g & 1))) * 512;
      }
      __builtin_amdgcn_global_load_lds(
          (const __attribute__((address_space(1))) unsigned int*)(src + laneoff),
          (__attribute__((address_space(3))) unsigned int*)&lds[bufi][f * 512],
          16, 0, 0);
    }
  };

  stage(0, 0);
  __syncthreads();
  int buf = 0;
  for (int ks = 0; ks < 16; ks++) {
    if (ks < 15) stage(ks + 1, buf ^ 1);
    half8 a[2][2], b[4][2];
    #pragma unroll
    for (int mi2 = 0; mi2 < 2; mi2++)
      #pragma unroll
      for (int kk = 0; kk < 2; kk++)
        a[mi2][kk] = *(const half8*)&lds[buf][(size_t)(((wm * 2 + mi2) * 2 + kk) * 512) + laneoff];
    #pragma unroll
    for (int ni2 = 0; ni2 < 4; ni2++)
      #pragma unroll
      for (int kk = 0; kk < 2; kk++)
        b[ni2][kk] = *(const half8*)&lds[buf][(size_t)(4096 + ((wn * 4 + ni2) * 2 + kk) * 512) + laneoff];
    #pragma unroll
    for (int kk = 0; kk < 2; kk++)
      #pragma unroll
      for (int mi2 = 0; mi2 < 2; mi2++)
        #pragma unroll
        for (int ni2 = 0; ni2 < 4; ni2++)
          acc[mi2][ni2] = __builtin_amdgcn_mfma_f32_16x16x32_f16(a[mi2][kk], b[ni2][kk], acc[mi2][ni2], 0, 0, 0);
    __syncthreads();   // drains vmcnt (next-buf stage) + waits readers
    buf ^= 1;
  }

  // ---- epilogue: partial store + last-block reduce ----
  int tileIdx = slab * 16 + y;
  float* myp = Upart + ((size_t)tileIdx * 16 + kslab) * 8192;
  #pragma unroll
  for (int mi2 = 0; mi2 < 2; mi2++) {
    int lr0 = (wm * 2 + mi2) * 16 + quad * 4;
    #pragma unroll
    for (int ni2 = 0; ni2 < 4; ni2++) {
      int lc = (wn * 4 + ni2) * 16 + lm;
      #pragma unroll
      for (int rr2 = 0; rr2 < 4; rr2++)
        myp[(size_t)(lr0 + rr2) * 128 + lc] = acc[mi2][ni2][rr2];
    }
  }
  __threadfence();      // each thread's stores visible device-wide
  __syncthreads();      // whole block's stores (+fences) done
  if (tid == 0) ticket_s = (int)atomicAdd(&tick[tileIdx], 1u);
  __syncthreads();
  if (ticket_s == 15) {
    __threadfence();    // acquire side
    const float4* pbase = (const float4*)(Upart + (size_t)tileIdx * 16 * 8192);
    const float sc = 1.f / 4096.f;
    #pragma unroll
    for (int e = 0; e < 8; e++) {
      int i = e * 256 + tid;
      float4 acc4 = pbase[i];
      #pragma unroll
      for (int p = 1; p < 16; p++) {
        float4 t = pbase[(size_t)p * 2048 + i];
        acc4.x += t.x; acc4.y += t.y; acc4.z += t.z; acc4.w += t.w;
      }
      acc4.x *= sc; acc4.y *= sc; acc4.z *= sc; acc4.w *= sc;
      int lr = i >> 5, lc4 = i & 31;
      *(float4*)&Us[(size_t)(mtb * 64 + lr) * 256 + ntb * 128 + lc4 * 4] = acc4;
    }
    if (tid == 0) tick[tileIdx] = 0u;   // self-reset for nS==1 looped reuse
  }
}

// ---------------- fused y0 = F @ Ttot GEMM + denorm + channel projection --------
// Block (px, b): rows = b*32..b*32+32 (all 32 channels of batch b), cols = 32 p.
// After the tile GEMM, denorm in LDS then 32x32x32 projection -> out directly.

__global__ __launch_bounds__(256) void y0final_k(const float* __restrict__ F,
                                                 const float* __restrict__ Ttot,
                                                 const float* __restrict__ stats,
                                                 const float* __restrict__ aw,
                                                 const float* __restrict__ ab,
                                                 const float* __restrict__ mlp_b,
                                                 const float* __restrict__ pw,
                                                 const float* __restrict__ pb,
                                                 float* __restrict__ out) {
  __shared__ float As[64][34];
  __shared__ float Bs[64][36];
  __shared__ float ys[32][33];
  __shared__ float pws[1024];
  int b = blockIdx.y;
  int col0 = blockIdx.x * 32;
  int row0 = b * 32;
  int tid = threadIdx.x;
  for (int t = tid; t < 1024; t += 256) pws[t] = pw[t];
  int tx = tid & 15, ty = tid >> 4;
  int kcA = (tid & 15) * 4, rA = tid >> 4;
  int ccB = (tid & 7) * 4, kkB = tid >> 3;
  int gr0 = row0 + rA, gr1 = row0 + rA + 16;
  float4 a0, a1, b0, b1;
  a0 = *(const float4*)&F[(size_t)gr0 * 512 + kcA];
  a1 = *(const float4*)&F[(size_t)gr1 * 512 + kcA];
  b0 = *(const float4*)&Ttot[(size_t)kkB * 512 + col0 + ccB];
  b1 = *(const float4*)&Ttot[(size_t)(kkB + 32) * 512 + col0 + ccB];
  float acc00 = 0.f, acc01 = 0.f, acc10 = 0.f, acc11 = 0.f;
  for (int kb = 0; kb < 512; kb += 64) {
    As[kcA+0][rA] = a0.x; As[kcA+1][rA] = a0.y; As[kcA+2][rA] = a0.z; As[kcA+3][rA] = a0.w;
    As[kcA+0][rA+16] = a1.x; As[kcA+1][rA+16] = a1.y; As[kcA+2][rA+16] = a1.z; As[kcA+3][rA+16] = a1.w;
    *(float4*)&Bs[kkB][ccB] = b0;
    *(float4*)&Bs[kkB+32][ccB] = b1;
    __syncthreads();
    if (kb + 64 < 512) {
      int kn = kb + 64;
      a0 = *(const float4*)&F[(size_t)gr0 * 512 + kn + kcA];
      a1 = *(const float4*)&F[(size_t)gr1 * 512 + kn + kcA];
      b0 = *(const float4*)&Ttot[(size_t)(kn + kkB) * 512 + col0 + ccB];
      b1 = *(const float4*)&Ttot[(size_t)(kn + kkB + 32) * 512 + col0 + ccB];
    }
    #pragma unroll
    for (int k = 0; k < 64; k++) {
      float2 av = *(float2*)&As[k][ty * 2];
      float2 bv = *(float2*)&Bs[k][tx * 2];
      acc00 += av.x * bv.x; acc01 += av.x * bv.y;
      acc10 += av.y * bv.x; acc11 += av.y * bv.y;
    }
    __syncthreads();
  }
  // denorm into ys[c][p]
  {
    int c0 = ty * 2, p0 = tx * 2;
    float mb0 = mlp_b[0];
    int r0 = row0 + c0;
    float mean0 = stats[r0],     sd0 = stats[512 + r0];
    float mean1 = stats[r0 + 1], sd1 = stats[512 + r0 + 1];
    float ia0 = 1.f / (aw[c0] + 1e-10f),     ab0 = ab[c0];
    float ia1 = 1.f / (aw[c0 + 1] + 1e-10f), ab1 = ab[c0 + 1];
    ys[c0][p0]     = ((acc00 + mb0) - ab0) * ia0 * sd0 + mean0;
    ys[c0][p0+1]   = ((acc01 + mb0) - ab0) * ia0 * sd0 + mean0;
    ys[c0+1][p0]   = ((acc10 + mb0) - ab1) * ia1 * sd1 + mean1;
    ys[c0+1][p0+1] = ((acc11 + mb0) - ab1) * ia1 * sd1 + mean1;
  }
  __syncthreads();
  // projection: out[b][col0+p][co] = pb[co] + sum_c ys[c][p]*pw[c][co]
  {
    int co = tid & 31, pb2 = tid >> 5;
    #pragma unroll
    for (int q = 0; q < 4; q++) {
      int p = pb2 + q * 8;
      float accv = pb[co];
      #pragma unroll
      for (int cc = 0; cc < 32; cc++) accv += ys[cc][p] * pws[cc * 32 + co];
      out[((size_t)b * 512 + col0 + p) * 32 + co] = accv;
    }
  }
}

// ---------------- launch ----------------

extern "C" void kernel_launch(void* const* d_in, const int* in_sizes, int n_in,
                              void* d_out, int out_size, void* d_ws, size_t ws_size,
                              hipStream_t stream) {
  const float* x_enc = (const float*)d_in[0];
  const float* aw = (const float*)d_in[4];
  const float* ab = (const float*)d_in[5];
  const float* wr[3] = {(const float*)d_in[6], (const float*)d_in[8], (const float*)d_in[10]};
  const float* wi[3] = {(const float*)d_in[7], (const float*)d_in[9], (const float*)d_in[11]};
  const float* mlp_w = (const float*)d_in[12];
  const float* mlp_b = (const float*)d_in[13];
  const float* proj_w = (const float*)d_in[14];
  const float* proj_b = (const float*)d_in[15];
  const float* Am[3]  = {(const float*)d_in[16], (const float*)d_in[19], (const float*)d_in[22]};
  const float* Bv[3]  = {(const float*)d_in[17], (const float*)d_in[20], (const float*)d_in[23]};
  const float* Em[3]  = {(const float*)d_in[18], (const float*)d_in[21], (const float*)d_in[24]};

  float* w = (float*)d_ws;
  float* F     = w; w += 512 * 512;
  float* stats = w; w += 1024;
  float* Kry   = w; w += 3 * 512 * 256;
  float* R     = w; w += 3 * 2 * 65536;
  float* U     = w; w += 3 * 512 * 256;   // U and Ttot contiguous (zeroed together)
  float* Ttot  = w; w += 512 * 512;
  float* Et    = w; w += 3 * 256 * 512;
  float* y0    = w; w += 512 * 512;       // kept in layout (unused) to preserve offsets
  float* Pp    = w; w += 3 * 65536 * 2;   // 3 slabs always (small)
  float* Upart = w; w += 768 * 8192;      // split-K partial tiles (24 MB)
  unsigned* tick = (unsigned*)w; w += 64; // per-output-tile ticket counters
  _Float16* Qf = (_Float16*)w;

  // f16 buffers: batched (3 slabs) if ws allows, else 1 shared slab per-scale loop
  size_t base_bytes = (size_t)((char*)Qf - (char*)d_ws);
  size_t slab_bytes = (size_t)(8388608 + 4194304) * 2;   // Qf + Wb per slab
  int nS = (ws_size >= base_bytes + 3 * slab_bytes) ? 3 : 1;
  _Float16* Wb = Qf + (size_t)nS * 8388608;
  (void)y0;

  // RevIN + transposes + kry init + ticket init + zeroing (+ wbigT), one launch
  int nW = (nS == 3) ? 768 : 0;
  prep2_k<<<1731 + nW, 256, 0, stream>>>(x_enc, aw, ab, F, stats,
                                         Am[0], Am[1], Am[2], Bv[0], Bv[1], Bv[2],
                                         Em[0], Em[1], Em[2], R, Kry, Et, U, tick,
                                         wr[0], wi[0], wr[1], wi[1], wr[2], wi[2], Wb);

  // Krylov doubling: Kry rows [2^j .. 2^(j+1)) = Kry[0..2^j) @ R_j ; R_{j+1} = R_j @ R_j
  // 9 sequential launches (depth-minimal: row 511 needs 9 dependent products).
  // Grid-wide sync alternatives measured: cg ~110us/sync (r5), hand-rolled
  // atomic barrier ~55us/sync (r6) -> launch-per-stage is the fastest option.
  for (int j = 0; j < 9; j++) {
    GJobs P{};
    int M = 1 << j;
    int cur = j & 1;
    int nz = 0;
    for (int s = 0; s < 3; s++) {
      float* Ks = Kry + (size_t)s * 131072;
      float* Rj = R + (size_t)s * 131072 + (size_t)cur * 65536;
      float* Rn = R + (size_t)s * 131072 + (size_t)(1 - cur) * 65536;
      P.j[nz++] = {Ks, Rj, Ks + (size_t)M * 256, nullptr, M, 256, 256, 0, 256, 0};
      if (j < 8) P.j[nz++] = {Rj, Rj, Rn, nullptr, 256, 256, 256, 0, 256, 0};
    }
    gemm32_k<<<dim3(8, 8, nz), 256, 0, stream>>>(P);
  }

  // Q build (2-phase), U = Q @ Wb via MFMA (split-K partials + ticket reduce)
  if (nS == 3) {
    qw_k<<<768, 256, 0, stream>>>(Kry, (float2*)Pp, wr[0], wi[0], wr[1], wi[1],
                                  wr[2], wi[2], Wb, 0, 768);
    qbuildB_k<<<768, 256, 0, stream>>>(Kry, (const float2*)Pp, Qf, 0);
    umfma_k<<<dim3(16, 16, 3), 256, 0, stream>>>(Qf, Wb, U, Upart, tick, 0);
  } else {
    for (int s = 0; s < 3; s++) {
      qw_k<<<512, 256, 0, stream>>>(Kry, (float2*)Pp, wr[0], wi[0], wr[1], wi[1],
                                    wr[2], wi[2], Wb, s, 256);
      qbuildB_k<<<256, 256, 0, stream>>>(Kry, (const float2*)Pp, Qf, s);
      umfma_k<<<dim3(16, 16, 1), 256, 0, stream>>>(Qf, Wb, U, Upart, tick, s);
    }
  }

  // Ttot += mlp_w[s] * U_s @ Et_s
  {
    GJobs P{};
    for (int s = 0; s < 3; s++)
      P.j[s] = {U + (size_t)s * 131072, Et + (size_t)s * 131072, Ttot,
                mlp_w + s, 512, 512, 256, 0, 256, 1};
    gemm32_k<<<dim3(16, 16, 3), 256, 0, stream>>>(P);
  }

  // fused: y0 = F @ Ttot, denorm, channel projection -> out
  y0final_k<<<dim3(16, 16), 256, 0, stream>>>(F, Ttot, stats, aw, ab, mlp_b,
                                              proj_w, proj_b, (float*)d_out);
}

// Round 11
// 331.607 us; speedup vs baseline: 1.4274x; 1.4274x over previous
//
#include <hip/hip_runtime.h>
#include <math.h>

#define SEQ 512
#define NORD 256
#define MODES 32
#define KBIG (NORD*MODES*2)   // 16384
#define PI_F 3.14159265358979323846f

typedef _Float16 half8 __attribute__((ext_vector_type(8)));
typedef float floatx4 __attribute__((ext_vector_type(4)));

// ---------------- latency-tolerant f32 GEMM: 32x32 tile, BK=64, reg prefetch ----

struct GJob {
  const float* A; const float* B; float* C; const float* scale_ptr;
  int M, N, lda, k0, k1, atomic;
};
struct GJobs { GJob j[6]; };

__global__ __launch_bounds__(256) void gemm32_k(GJobs P) {
  GJob jb = P.j[blockIdx.z];
  int col0 = blockIdx.x * 32;
  int row0 = blockIdx.y * 32;
  if (row0 >= jb.M || col0 >= jb.N) return;
  __shared__ float As[64][34];   // [k][m]; pad 34 keeps b64 reads aligned, 4-way store conflicts only
  __shared__ float Bs[64][36];   // [k][n]; pad 36 keeps float4 stores 16B-aligned
  int tid = threadIdx.x;
  int tx = tid & 15, ty = tid >> 4;
  const float* A = jb.A; const float* B = jb.B;
  int M = jb.M, N = jb.N, lda = jb.lda;
  int kcA = (tid & 15) * 4, rA = tid >> 4;
  int ccB = (tid & 7) * 4, kkB = tid >> 3;
  int gr0 = row0 + rA, gr1 = row0 + rA + 16;
  const float4 z4 = make_float4(0.f, 0.f, 0.f, 0.f);
  float4 a0, a1, b0, b1;
  {
    int kb = jb.k0;
    a0 = (gr0 < M) ? *(const float4*)&A[(size_t)gr0 * lda + kb + kcA] : z4;
    a1 = (gr1 < M) ? *(const float4*)&A[(size_t)gr1 * lda + kb + kcA] : z4;
    b0 = *(const float4*)&B[(size_t)(kb + kkB) * N + col0 + ccB];
    b1 = *(const float4*)&B[(size_t)(kb + kkB + 32) * N + col0 + ccB];
  }
  float acc00 = 0.f, acc01 = 0.f, acc10 = 0.f, acc11 = 0.f;
  for (int kb = jb.k0; kb < jb.k1; kb += 64) {
    As[kcA+0][rA] = a0.x; As[kcA+1][rA] = a0.y; As[kcA+2][rA] = a0.z; As[kcA+3][rA] = a0.w;
    As[kcA+0][rA+16] = a1.x; As[kcA+1][rA+16] = a1.y; As[kcA+2][rA+16] = a1.z; As[kcA+3][rA+16] = a1.w;
    *(float4*)&Bs[kkB][ccB] = b0;
    *(float4*)&Bs[kkB+32][ccB] = b1;
    __syncthreads();
    if (kb + 64 < jb.k1) {
      int kn = kb + 64;
      a0 = (gr0 < M) ? *(const float4*)&A[(size_t)gr0 * lda + kn + kcA] : z4;
      a1 = (gr1 < M) ? *(const float4*)&A[(size_t)gr1 * lda + kn + kcA] : z4;
      b0 = *(const float4*)&B[(size_t)(kn + kkB) * N + col0 + ccB];
      b1 = *(const float4*)&B[(size_t)(kn + kkB + 32) * N + col0 + ccB];
    }
    #pragma unroll
    for (int k = 0; k < 64; k++) {
      float2 av = *(float2*)&As[k][ty * 2];
      float2 bv = *(float2*)&Bs[k][tx * 2];
      acc00 += av.x * bv.x; acc01 += av.x * bv.y;
      acc10 += av.y * bv.x; acc11 += av.y * bv.y;
    }
    __syncthreads();
  }
  float sc = jb.scale_ptr ? *jb.scale_ptr : 1.f;
  int gr = row0 + ty * 2, gc = col0 + tx * 2;
  float v00 = acc00 * sc, v01 = acc01 * sc, v10 = acc10 * sc, v11 = acc11 * sc;
  if (jb.atomic) {
    if (gr < M)     { atomicAdd(&jb.C[(size_t)gr * N + gc], v00);     atomicAdd(&jb.C[(size_t)gr * N + gc + 1], v01); }
    if (gr + 1 < M) { atomicAdd(&jb.C[(size_t)(gr+1) * N + gc], v10); atomicAdd(&jb.C[(size_t)(gr+1) * N + gc + 1], v11); }
  } else {
    if (gr < M)     { jb.C[(size_t)gr * N + gc] = v00;     jb.C[(size_t)gr * N + gc + 1] = v01; }
    if (gr + 1 < M) { jb.C[(size_t)(gr+1) * N + gc] = v10; jb.C[(size_t)(gr+1) * N + gc + 1] = v11; }
  }
}

// ---------------- merged prep: RevIN + LDS-tiled transposes + kry init + zeroing
// + (optionally) wbigT weight build in blocks [1731, 1731+nW) ------------------

__global__ __launch_bounds__(256) void prep2_k(const float* __restrict__ x_enc,
                                               const float* __restrict__ aw,
                                               const float* __restrict__ ab,
                                               float* __restrict__ F,
                                               float* __restrict__ stats,
                                               const float* A0, const float* A1, const float* A2,
                                               const float* B0, const float* B1, const float* B2,
                                               const float* E0, const float* E1, const float* E2,
                                               float* R, float* Kry, float* Et, float* Z,
                                               const float* wr0, const float* wi0,
                                               const float* wr1, const float* wi1,
                                               const float* wr2, const float* wi2,
                                               _Float16* __restrict__ Wt) {
  __shared__ float tile[32][33];
  __shared__ float ws1[4], ws2[4];
  __shared__ float mean_s, istd_s;
  int bid = blockIdx.x;
  int tid = threadIdx.x;
  if (bid < 512) {
    // ---- RevIN ----
    int row = bid;
    int b = row >> 5, c = row & 31;
    const float* xp = x_enc + (size_t)b * SEQ * 32 + c;
    float v0 = xp[(size_t)tid * 32];
    float v1 = xp[(size_t)(tid + 256) * 32];
    float s = v0 + v1, s2 = v0 * v0 + v1 * v1;
    for (int off = 32; off; off >>= 1) {
      s  += __shfl_down(s,  off, 64);
      s2 += __shfl_down(s2, off, 64);
    }
    int wid = tid >> 6, lane = tid & 63;
    if (lane == 0) { ws1[wid] = s; ws2[wid] = s2; }
    __syncthreads();
    if (tid == 0) {
      float t1 = ws1[0] + ws1[1] + ws1[2] + ws1[3];
      float t2 = ws2[0] + ws2[1] + ws2[2] + ws2[3];
      float mean = t1 / 512.f;
      float var = t2 / 512.f - mean * mean;
      float sd = sqrtf(var + 1e-5f);
      mean_s = mean; istd_s = 1.f / sd;
      stats[row] = mean; stats[512 + row] = sd;
    }
    __syncthreads();
    float w = aw[c], bb = ab[c];
    float m = mean_s, is = istd_s;
    F[(size_t)row * SEQ + tid]       = (v0 - m) * is * w + bb;
    F[(size_t)row * SEQ + tid + 256] = (v1 - m) * is * w + bb;
  } else if (bid < 704) {
    // ---- R[m][i2] = A[i2][m], 32x32 LDS tiles, both sides coalesced ----
    int b2 = bid - 512;
    int scl = b2 >> 6, t = b2 & 63;
    int ti = t >> 3, tm = t & 7;
    const float* A = scl == 0 ? A0 : (scl == 1 ? A1 : A2);
    float* Rd = R + (size_t)scl * 2 * 65536;
    int tx = tid & 31, ty0 = tid >> 5;
    int i0 = ti * 32, m0 = tm * 32;
    #pragma unroll
    for (int r = 0; r < 4; r++) {
      int ty = ty0 + r * 8;
      tile[ty][tx] = A[(size_t)(i0 + ty) * 256 + m0 + tx];
    }
    __syncthreads();
    #pragma unroll
    for (int r = 0; r < 4; r++) {
      int ty = ty0 + r * 8;
      Rd[(size_t)(m0 + ty) * 256 + i0 + tx] = tile[tx][ty];
    }
  } else if (bid < 1088) {
    // ---- Et[o][p] = E[base+p][o], 32x32 LDS tiles ----
    int b2 = bid - 704;
    int scl = b2 >> 7, t = b2 & 127;
    int tp = t >> 3, to = t & 7;
    const float* E; int rows;
    if (scl == 0) { E = E0; rows = 512; }
    else if (scl == 1) { E = E1; rows = 1024; }
    else { E = E2; rows = 2048; }
    int base = rows - 512;
    int p0 = tp * 32, o0 = to * 32;
    int tx = tid & 31, ty0 = tid >> 5;
    #pragma unroll
    for (int r = 0; r < 4; r++) {
      int ty = ty0 + r * 8;
      tile[ty][tx] = E[(size_t)(base + p0 + ty) * 256 + o0 + tx];
    }
    __syncthreads();
    #pragma unroll
    for (int r = 0; r < 4; r++) {
      int ty = ty0 + r * 8;
      Et[(size_t)scl * 131072 + (size_t)(o0 + ty) * 512 + p0 + tx] = tile[tx][ty];
    }
  } else if (bid < 1091) {
    int scl = bid - 1088;
    const float* B = scl == 0 ? B0 : (scl == 1 ? B1 : B2);
    Kry[(size_t)scl * 512 * 256 + tid] = B[tid];
  } else if (bid < 1731) {
    int idx = (bid - 1091) * 256 + tid;   // 640 blocks * 256 = 163840 float4 = 655360 floats
    ((float4*)Z)[idx] = make_float4(0.f, 0.f, 0.f, 0.f);
  } else {
    // ---- wbigT: f16 weights in fragment order, x4096 scale (nS==3 path) ----
    int bg = bid - 1731;
    int slab = bg >> 8;
    int s = slab;
    int r = bg & 255;
    int og = r >> 3, iq = r & 7;
    const float* wr = s == 0 ? wr0 : (s == 1 ? wr1 : wr2);
    const float* wi = s == 0 ? wi0 : (s == 1 ? wi1 : wi2);
    unsigned int* Wd = (unsigned int*)(Wt + (size_t)slab * 4194304);
    int ol = tid >> 5, k = tid & 31;
    int o = og * 8 + ol;
    float sn, cn; __sincosf((2.f * PI_F / 512.f) * (float)k, &sn, &cn);
    float g = ((k == 0) ? (1.f / 512.f) : (2.f / 512.f)) * 4096.f;
    float gc = g * cn, gs = g * sn;
    size_t obase = (size_t)(o >> 4) * 512;
    int osub = (((k >> 2) & 3) * 16 + (o & 15)) * 4 + (k & 3);
    for (int ii = 0; ii < 32; ii++) {
      int i = iq * 32 + ii;
      float a = wr[(size_t)i * 8192 + o * 32 + k];
      float b = wi[(size_t)i * 8192 + o * 32 + k];
      float v0 = gc * a + gs * b;
      float v1 = gs * a - gc * b;
      _Float16 h0 = (_Float16)v0, h1 = (_Float16)v1;
      unsigned short u0, u1;
      __builtin_memcpy(&u0, &h0, 2); __builtin_memcpy(&u1, &h1, 2);
      Wd[(obase + (size_t)(i * 2 + (k >> 4))) * 256 + osub] = (unsigned int)u0 | ((unsigned int)u1 << 16);
    }
  }
}

// ---------------- qbuild: 2-phase chunked prefix over m (batched over scales) ----
//
// Q is written in MFMA-FRAGMENT ORDER so the GEMM streams it with zero LDS
// address math. All trig args are (2pi/512)*t, t in [0,512): per-block LDS
// table of (cos, -sin) built with the same __sincosf -> bit-identical values.

__global__ __launch_bounds__(256) void qbuildB_k(const float* __restrict__ Kry,
                                                 const float2* __restrict__ Pp,
                                                 _Float16* __restrict__ Qf, int s0) {
  int bg = blockIdx.x;
  int slab = bg >> 8;
  int s = s0 + slab;
  int r = bg & 255;
  int ig = r & 31, c = r >> 5;
  const float* Kry_s = Kry + (size_t)s * 131072;
  const float2* P = Pp + (size_t)s * 65536;
  uint4* Qd4 = (uint4*)(Qf + (size_t)slab * 8388608);
  int tid = threadIdx.x;
  int k = tid & 31, il = tid >> 5;
  int i = ig * 8 + il;
  __shared__ __align__(16) unsigned int buf[16 * 260];  // stride 260: bank step 4, 2-way only
  __shared__ float2 tbl[512];                           // (cos, -sin) per 512th turn
  {
    const float step = 2.f * PI_F / 512.f;
    for (int t = tid; t < 512; t += 256) {
      float sn, cn; __sincosf(step * (float)t, &sn, &cn);
      tbl[t] = make_float2(cn, -sn);
    }
  }
  __syncthreads();
  float ar = 0.f, ai = 0.f;
  for (int cp = 0; cp < c; cp++) {
    float2 p = P[(size_t)(cp * 32 + k) * 256 + i];
    ar += p.x; ai += p.y;
  }
  int m0 = c * 64;
  int st_low = tid & 15;
  int part_base = tid >> 4;      // 0..15
  for (int mb = 0; mb < 64; mb += 16) {
    #pragma unroll
    for (int mm = 0; mm < 16; mm++) {
      int m = m0 + mb + mm;
      float kap = Kry_s[(size_t)m * 256 + i];
      float2 cs = tbl[(k * m) & 511];
      ar += kap * cs.x; ai += kap * cs.y;
      int st = 511 - m;
      float2 cs2 = tbl[(k * st) & 511];
      float cn2 = cs2.x, sn2 = -cs2.y;
      float qr = ar * cn2 + ai * sn2;
      float qi = ai * cn2 - ar * sn2;
      qr = fminf(fmaxf(qr, -60000.f), 60000.f);
      qi = fminf(fmaxf(qi, -60000.f), 60000.f);
      _Float16 h0 = (_Float16)qr, h1 = (_Float16)qi;
      unsigned short u0, u1;
      __builtin_memcpy(&u0, &h0, 2); __builtin_memcpy(&u1, &h1, 2);
      buf[(st & 15) * 260 + il * 32 + k] = (unsigned int)u0 | ((unsigned int)u1 << 16);
    }
    __syncthreads();
    int st_base = 496 - m0 - mb;          // multiple of 16
    int st = st_base + st_low;
    size_t rowbase = (size_t)(st >> 4) * 512;
    #pragma unroll
    for (int p = 0; p < 4; p++) {
      int part = part_base + p * 16;      // 0..63 = (il<<3)|k4
      int ilw = part >> 3, k4 = part & 7;
      int iw = ig * 8 + ilw;
      size_t g = (rowbase + (size_t)(iw * 2 + (k4 >> 2))) * 64
               + (size_t)((k4 & 3) * 16 + st_low);
      Qd4[g] = *(const uint4*)&buf[st_low * 260 + ilw * 32 + k4 * 4];
    }
    __syncthreads();
  }
}

// ---------------- merged: qbuildA (bid<nA) + Wbig^T build (bid>=nA) -------------
// (wbigT branch only used on the nS==1 fallback path; nS==3 does wbigT in prep2)

__global__ __launch_bounds__(256) void qw_k(const float* __restrict__ Kry,
                                            float2* __restrict__ Pp,
                                            const float* wr0, const float* wi0,
                                            const float* wr1, const float* wi1,
                                            const float* wr2, const float* wi2,
                                            _Float16* __restrict__ Wt, int s0, int nA) {
  __shared__ float2 tbl[512];
  int bid = blockIdx.x;
  int tid = threadIdx.x;
  if (bid < nA) {
    // ---- qbuildA: chunk partial DFT sums (table-driven; k is block-uniform
    // so the tbl read is an LDS broadcast) ----
    {
      const float step = 2.f * PI_F / 512.f;
      for (int t = tid; t < 512; t += 256) {
        float sn, cn; __sincosf(step * (float)t, &sn, &cn);
        tbl[t] = make_float2(cn, -sn);
      }
    }
    __syncthreads();
    int bg = bid;
    int s = s0 + (bg >> 8);
    int r = bg & 255;
    int k = r & 31, c = r >> 5;
    const float* Kry_s = Kry + (size_t)s * 131072;
    float2* P = Pp + (size_t)s * 65536;
    int i = tid;
    float ar = 0.f, ai = 0.f;
    int m0 = c * 64;
    for (int mm = 0; mm < 64; mm++) {
      int m = m0 + mm;
      float kap = Kry_s[(size_t)m * 256 + i];
      float2 cs = tbl[(k * m) & 511];
      ar += kap * cs.x; ai += kap * cs.y;
    }
    P[(size_t)(c * 32 + k) * 256 + i] = make_float2(ar, ai);
  } else {
    // ---- wbigT: f16 weights in fragment order, x4096 scale ----
    int bg = bid - nA;
    int slab = bg >> 8;
    int s = s0 + slab;
    int r = bg & 255;
    int og = r >> 3, iq = r & 7;
    const float* wr = s == 0 ? wr0 : (s == 1 ? wr1 : wr2);
    const float* wi = s == 0 ? wi0 : (s == 1 ? wi1 : wi2);
    unsigned int* Wd = (unsigned int*)(Wt + (size_t)slab * 4194304);
    int ol = tid >> 5, k = tid & 31;
    int o = og * 8 + ol;
    float sn, cn; __sincosf((2.f * PI_F / 512.f) * (float)k, &sn, &cn);
    float g = ((k == 0) ? (1.f / 512.f) : (2.f / 512.f)) * 4096.f;
    float gc = g * cn, gs = g * sn;
    size_t obase = (size_t)(o >> 4) * 512;
    int osub = (((k >> 2) & 3) * 16 + (o & 15)) * 4 + (k & 3);
    for (int ii = 0; ii < 32; ii++) {
      int i = iq * 32 + ii;
      float a = wr[(size_t)i * 8192 + o * 32 + k];
      float b = wi[(size_t)i * 8192 + o * 32 + k];
      float v0 = gc * a + gs * b;
      float v1 = gs * a - gc * b;
      _Float16 h0 = (_Float16)v0, h1 = (_Float16)v1;
      unsigned short u0, u1;
      __builtin_memcpy(&u0, &h0, 2); __builtin_memcpy(&u1, &h1, 2);
      Wd[(obase + (size_t)(i * 2 + (k >> 4))) * 256 + osub] = (unsigned int)u0 | ((unsigned int)u1 << 16);
    }
  }
}

// ---------------- U = Q @ Wb, LDS-staged dbuf MFMA, split-K partials ------------
// Epilogue: plain per-instruction-coalesced float4 stores of this block's
// partial tile (NO fence, NO atomics, NO in-kernel reduce — r9's in-kernel
// ticket+__threadfence caused per-block L2 writebacks, 4.3x regression).
// Cross-XCD visibility comes free from the kernel boundary; ureduce_k sums.

__global__ __launch_bounds__(256) void umfma_k(const _Float16* __restrict__ Qf,
                                               const _Float16* __restrict__ Wt,
                                               float4* __restrict__ Upart4) {
  __shared__ __align__(16) _Float16 lds[2][12288];   // 24 frags x 512 halfs x dbuf = 48KB
  int kslab = blockIdx.x;          // 0..15
  int y = blockIdx.y;              // 0..15
  int slab = blockIdx.z;
  int mtb = y >> 1, ntb = y & 1;   // 8 x 64-row tiles, 2 x 128-col tiles
  const _Float16* Q = Qf + (size_t)slab * 8388608;
  const _Float16* W = Wt + (size_t)slab * 4194304;
  int tid = threadIdx.x;
  int w = tid >> 6, lane = tid & 63;
  int wm = w >> 1, wn = w & 1;
  int mt0g = mtb * 4;              // block-local mt 0..3 -> global mt0g..+3
  int nt0g = ntb * 8;              // block-local nt 0..7
  int ktg0 = kslab * 32;
  size_t laneoff = (size_t)lane * 8;

  floatx4 acc[2][4];
  #pragma unroll
  for (int a = 0; a < 2; a++)
    #pragma unroll
    for (int b = 0; b < 4; b++) acc[a][b] = (floatx4)(0.f);

  // stage: 24 fragments (8 A + 16 B), 6 per wave, f*512 halfs into LDS
  auto stage = [&](int ks, int bufi) {
    int ktg = ktg0 + ks * 2;
    #pragma unroll
    for (int q = 0; q < 6; q++) {
      int f = w * 6 + q;
      const _Float16* src;
      if (f < 8) {
        src = Q + (((size_t)(mt0g + (f >> 1)) * 512) + (size_t)(ktg + (f & 1))) * 512;
      } else {
        int g = f - 8;
        src = W + (((size_t)(nt0g + (g >> 1)) * 512) + (size_t)(ktg + (g & 1))) * 512;
      }
      __builtin_amdgcn_global_load_lds(
          (const __attribute__((address_space(1))) unsigned int*)(src + laneoff),
          (__attribute__((address_space(3))) unsigned int*)&lds[bufi][f * 512],
          16, 0, 0);
    }
  };

  stage(0, 0);
  __syncthreads();
  int buf = 0;
  for (int ks = 0; ks < 16; ks++) {
    if (ks < 15) stage(ks + 1, buf ^ 1);
    half8 a[2][2], b[4][2];
    #pragma unroll
    for (int mi2 = 0; mi2 < 2; mi2++)
      #pragma unroll
      for (int kk = 0; kk < 2; kk++)
        a[mi2][kk] = *(const half8*)&lds[buf][(size_t)(((wm * 2 + mi2) * 2 + kk) * 512) + laneoff];
    #pragma unroll
    for (int ni2 = 0; ni2 < 4; ni2++)
      #pragma unroll
      for (int kk = 0; kk < 2; kk++)
        b[ni2][kk] = *(const half8*)&lds[buf][(size_t)(4096 + ((wn * 4 + ni2) * 2 + kk) * 512) + laneoff];
    #pragma unroll
    for (int kk = 0; kk < 2; kk++)
      #pragma unroll
      for (int mi2 = 0; mi2 < 2; mi2++)
        #pragma unroll
        for (int ni2 = 0; ni2 < 4; ni2++)
          acc[mi2][ni2] = __builtin_amdgcn_mfma_f32_16x16x32_f16(a[mi2][kk], b[ni2][kk], acc[mi2][ni2], 0, 0, 0);
    __syncthreads();   // drains vmcnt (next-buf stage) + waits readers
    buf ^= 1;
  }

  // partial store: slot (j*256 + tid) -> per-instruction fully coalesced
  int tileIdx = slab * 16 + y;
  float4* myp = Upart4 + ((size_t)tileIdx * 16 + kslab) * 2048;
  #pragma unroll
  for (int mi2 = 0; mi2 < 2; mi2++)
    #pragma unroll
    for (int ni2 = 0; ni2 < 4; ni2++)
      myp[(mi2 * 4 + ni2) * 256 + tid] = *(float4*)&acc[mi2][ni2];
}

// ---------------- ureduce: sum 16 split-K partials -> U (deterministic order) ---
// element e of tile t: j=e>>8 (acc slot), tsrc=e&255 (producer thread); the
// float4 spans 4 consecutive ROWS at one col of the 64x128 tile.

__global__ __launch_bounds__(256) void ureduce_k(const float4* __restrict__ Upart4,
                                                 float* __restrict__ U, int s0) {
  int g = blockIdx.x * 256 + threadIdx.x;
  int tileIdx = g >> 11;
  int e = g & 2047;
  int j = e >> 8, tsrc = e & 255;
  int mi2 = j >> 2, ni2 = j & 3;
  int w = tsrc >> 6, lane = tsrc & 63;
  int wm = w >> 1, wn = w & 1;
  int quad = lane >> 4, lm = lane & 15;
  int y = tileIdx & 15;
  int mtb = y >> 1, ntb = y & 1;
  int s = s0 + (tileIdx >> 4);
  const float4* pb = Upart4 + (size_t)tileIdx * 16 * 2048 + e;
  float4 a = pb[0];
  #pragma unroll
  for (int p = 1; p < 16; p++) {
    float4 t = pb[(size_t)p * 2048];
    a.x += t.x; a.y += t.y; a.z += t.z; a.w += t.w;
  }
  const float sc = 1.f / 4096.f;
  int row = mtb * 64 + (wm * 2 + mi2) * 16 + quad * 4;
  int col = ntb * 128 + (wn * 4 + ni2) * 16 + lm;
  float* Us = U + (size_t)s * 131072;
  Us[(size_t)(row + 0) * 256 + col] = a.x * sc;
  Us[(size_t)(row + 1) * 256 + col] = a.y * sc;
  Us[(size_t)(row + 2) * 256 + col] = a.z * sc;
  Us[(size_t)(row + 3) * 256 + col] = a.w * sc;
}

// ---------------- fused y0 = F @ Ttot GEMM + denorm + channel projection --------
// Block (px, b): rows = b*32..b*32+32 (all 32 channels of batch b), cols = 32 p.
// After the tile GEMM, denorm in LDS then 32x32x32 projection -> out directly.

__global__ __launch_bounds__(256) void y0final_k(const float* __restrict__ F,
                                                 const float* __restrict__ Ttot,
                                                 const float* __restrict__ stats,
                                                 const float* __restrict__ aw,
                                                 const float* __restrict__ ab,
                                                 const float* __restrict__ mlp_b,
                                                 const float* __restrict__ pw,
                                                 const float* __restrict__ pb,
                                                 float* __restrict__ out) {
  __shared__ float As[64][34];
  __shared__ float Bs[64][36];
  __shared__ float ys[32][33];
  __shared__ float pws[1024];
  int b = blockIdx.y;
  int col0 = blockIdx.x * 32;
  int row0 = b * 32;
  int tid = threadIdx.x;
  for (int t = tid; t < 1024; t += 256) pws[t] = pw[t];
  int tx = tid & 15, ty = tid >> 4;
  int kcA = (tid & 15) * 4, rA = tid >> 4;
  int ccB = (tid & 7) * 4, kkB = tid >> 3;
  int gr0 = row0 + rA, gr1 = row0 + rA + 16;
  float4 a0, a1, b0, b1;
  a0 = *(const float4*)&F[(size_t)gr0 * 512 + kcA];
  a1 = *(const float4*)&F[(size_t)gr1 * 512 + kcA];
  b0 = *(const float4*)&Ttot[(size_t)kkB * 512 + col0 + ccB];
  b1 = *(const float4*)&Ttot[(size_t)(kkB + 32) * 512 + col0 + ccB];
  float acc00 = 0.f, acc01 = 0.f, acc10 = 0.f, acc11 = 0.f;
  for (int kb = 0; kb < 512; kb += 64) {
    As[kcA+0][rA] = a0.x; As[kcA+1][rA] = a0.y; As[kcA+2][rA] = a0.z; As[kcA+3][rA] = a0.w;
    As[kcA+0][rA+16] = a1.x; As[kcA+1][rA+16] = a1.y; As[kcA+2][rA+16] = a1.z; As[kcA+3][rA+16] = a1.w;
    *(float4*)&Bs[kkB][ccB] = b0;
    *(float4*)&Bs[kkB+32][ccB] = b1;
    __syncthreads();
    if (kb + 64 < 512) {
      int kn = kb + 64;
      a0 = *(const float4*)&F[(size_t)gr0 * 512 + kn + kcA];
      a1 = *(const float4*)&F[(size_t)gr1 * 512 + kn + kcA];
      b0 = *(const float4*)&Ttot[(size_t)(kn + kkB) * 512 + col0 + ccB];
      b1 = *(const float4*)&Ttot[(size_t)(kn + kkB + 32) * 512 + col0 + ccB];
    }
    #pragma unroll
    for (int k = 0; k < 64; k++) {
      float2 av = *(float2*)&As[k][ty * 2];
      float2 bv = *(float2*)&Bs[k][tx * 2];
      acc00 += av.x * bv.x; acc01 += av.x * bv.y;
      acc10 += av.y * bv.x; acc11 += av.y * bv.y;
    }
    __syncthreads();
  }
  // denorm into ys[c][p]
  {
    int c0 = ty * 2, p0 = tx * 2;
    float mb0 = mlp_b[0];
    int r0 = row0 + c0;
    float mean0 = stats[r0],     sd0 = stats[512 + r0];
    float mean1 = stats[r0 + 1], sd1 = stats[512 + r0 + 1];
    float ia0 = 1.f / (aw[c0] + 1e-10f),     ab0 = ab[c0];
    float ia1 = 1.f / (aw[c0 + 1] + 1e-10f), ab1 = ab[c0 + 1];
    ys[c0][p0]     = ((acc00 + mb0) - ab0) * ia0 * sd0 + mean0;
    ys[c0][p0+1]   = ((acc01 + mb0) - ab0) * ia0 * sd0 + mean0;
    ys[c0+1][p0]   = ((acc10 + mb0) - ab1) * ia1 * sd1 + mean1;
    ys[c0+1][p0+1] = ((acc11 + mb0) - ab1) * ia1 * sd1 + mean1;
  }
  __syncthreads();
  // projection: out[b][col0+p][co] = pb[co] + sum_c ys[c][p]*pw[c][co]
  {
    int co = tid & 31; int pb2 = tid >> 5;
    #pragma unroll
    for (int q = 0; q < 4; q++) {
      int p = pb2 + q * 8;
      float accv = pb[co];
      #pragma unroll
      for (int cc = 0; cc < 32; cc++) accv += ys[cc][p] * pws[cc * 32 + co];
      out[((size_t)b * 512 + col0 + p) * 32 + co] = accv;
    }
  }
}

// ---------------- launch ----------------

extern "C" void kernel_launch(void* const* d_in, const int* in_sizes, int n_in,
                              void* d_out, int out_size, void* d_ws, size_t ws_size,
                              hipStream_t stream) {
  const float* x_enc = (const float*)d_in[0];
  const float* aw = (const float*)d_in[4];
  const float* ab = (const float*)d_in[5];
  const float* wr[3] = {(const float*)d_in[6], (const float*)d_in[8], (const float*)d_in[10]};
  const float* wi[3] = {(const float*)d_in[7], (const float*)d_in[9], (const float*)d_in[11]};
  const float* mlp_w = (const float*)d_in[12];
  const float* mlp_b = (const float*)d_in[13];
  const float* proj_w = (const float*)d_in[14];
  const float* proj_b = (const float*)d_in[15];
  const float* Am[3]  = {(const float*)d_in[16], (const float*)d_in[19], (const float*)d_in[22]};
  const float* Bv[3]  = {(const float*)d_in[17], (const float*)d_in[20], (const float*)d_in[23]};
  const float* Em[3]  = {(const float*)d_in[18], (const float*)d_in[21], (const float*)d_in[24]};

  float* w = (float*)d_ws;
  float* F     = w; w += 512 * 512;
  float* stats = w; w += 1024;
  float* Kry   = w; w += 3 * 512 * 256;
  float* R     = w; w += 3 * 2 * 65536;
  float* U     = w; w += 3 * 512 * 256;   // U and Ttot contiguous (zeroed together)
  float* Ttot  = w; w += 512 * 512;
  float* Et    = w; w += 3 * 256 * 512;
  float* y0    = w; w += 512 * 512;       // kept in layout (unused) to preserve offsets
  float* Pp    = w; w += 3 * 65536 * 2;   // 3 slabs always (small)
  float* Upart = w; w += 768 * 8192;      // split-K partial tiles (24 MB)
  _Float16* Qf = (_Float16*)w;

  // f16 buffers: batched (3 slabs) if ws allows, else 1 shared slab per-scale loop
  size_t base_bytes = (size_t)((char*)Qf - (char*)d_ws);
  size_t slab_bytes = (size_t)(8388608 + 4194304) * 2;   // Qf + Wb per slab
  int nS = (ws_size >= base_bytes + 3 * slab_bytes) ? 3 : 1;
  _Float16* Wb = Qf + (size_t)nS * 8388608;
  (void)y0;

  // RevIN + transposes + kry init + zeroing (+ wbigT when batched), one launch
  int nW = (nS == 3) ? 768 : 0;
  prep2_k<<<1731 + nW, 256, 0, stream>>>(x_enc, aw, ab, F, stats,
                                         Am[0], Am[1], Am[2], Bv[0], Bv[1], Bv[2],
                                         Em[0], Em[1], Em[2], R, Kry, Et, U,
                                         wr[0], wi[0], wr[1], wi[1], wr[2], wi[2], Wb);

  // Krylov doubling: Kry rows [2^j .. 2^(j+1)) = Kry[0..2^j) @ R_j ; R_{j+1} = R_j @ R_j
  // 9 sequential launches (depth-minimal: row 511 needs 9 dependent products).
  // Grid-wide sync alternatives measured: cg ~110us/sync (r5), hand-rolled
  // atomic barrier ~55us/sync (r6) -> launch-per-stage is the fastest option.
  for (int j = 0; j < 9; j++) {
    GJobs P{};
    int M = 1 << j;
    int cur = j & 1;
    int nz = 0;
    for (int s = 0; s < 3; s++) {
      float* Ks = Kry + (size_t)s * 131072;
      float* Rj = R + (size_t)s * 131072 + (size_t)cur * 65536;
      float* Rn = R + (size_t)s * 131072 + (size_t)(1 - cur) * 65536;
      P.j[nz++] = {Ks, Rj, Ks + (size_t)M * 256, nullptr, M, 256, 256, 0, 256, 0};
      if (j < 8) P.j[nz++] = {Rj, Rj, Rn, nullptr, 256, 256, 256, 0, 256, 0};
    }
    gemm32_k<<<dim3(8, 8, nz), 256, 0, stream>>>(P);
  }

  // Q build (2-phase), U = Q @ Wb via MFMA (split-K partials, boundary-coherent),
  // then ureduce sums the 16 partials per tile.
  if (nS == 3) {
    qw_k<<<768, 256, 0, stream>>>(Kry, (float2*)Pp, wr[0], wi[0], wr[1], wi[1],
                                  wr[2], wi[2], Wb, 0, 768);
    qbuildB_k<<<768, 256, 0, stream>>>(Kry, (const float2*)Pp, Qf, 0);
    umfma_k<<<dim3(16, 16, 3), 256, 0, stream>>>(Qf, Wb, (float4*)Upart);
    ureduce_k<<<384, 256, 0, stream>>>((const float4*)Upart, U, 0);
  } else {
    for (int s = 0; s < 3; s++) {
      qw_k<<<512, 256, 0, stream>>>(Kry, (float2*)Pp, wr[0], wi[0], wr[1], wi[1],
                                    wr[2], wi[2], Wb, s, 256);
      qbuildB_k<<<256, 256, 0, stream>>>(Kry, (const float2*)Pp, Qf, s);
      umfma_k<<<dim3(16, 16, 1), 256, 0, stream>>>(Qf, Wb, (float4*)Upart);
      ureduce_k<<<128, 256, 0, stream>>>((const float4*)Upart, U, s);
    }
  }

  // Ttot += mlp_w[s] * U_s @ Et_s
  {
    GJobs P{};
    for (int s = 0; s < 3; s++)
      P.j[s] = {U + (size_t)s * 131072, Et + (size_t)s * 131072, Ttot,
                mlp_w + s, 512, 512, 256, 0, 256, 1};
    gemm32_k<<<dim3(16, 16, 3), 256, 0, stream>>>(P);
  }

  // fused: y0 = F @ Ttot, denorm, channel projection -> out
  y0final_k<<<dim3(16, 16), 256, 0, stream>>>(F, Ttot, stats, aw, ab, mlp_b,
                                              proj_w, proj_b, (float*)d_out);
}